// Round 18
// baseline (51.058 us; speedup 1.0000x reference)
//
#include <hip/hip_runtime.h>
#include <hip/hip_bf16.h>

#define NB 8
#define NS 2048
#define ND 1024
#define NH 64
#define NM (NB*NS)   // 16384 rows

typedef __attribute__((ext_vector_type(8))) short short8;
typedef __attribute__((ext_vector_type(4))) short short4v;
typedef __attribute__((ext_vector_type(4))) float f32x4;
typedef __attribute__((ext_vector_type(4))) float f4;
typedef __attribute__((ext_vector_type(2))) unsigned int uint2v;

// q pre-scale: fold 1/sqrt(64) and log2(e) so attention uses exp2 directly.
#define QSCALE (0.125f * 1.44269504088896340736f)

__device__ __forceinline__ unsigned short f2bf(float f) {
    union { __hip_bfloat16 h; unsigned short u; } cv;
    cv.h = __float2bfloat16(f);   // HW RTNE convert
    return cv.u;
}

// Barrier WITHOUT the vmcnt(0) drain __syncthreads would emit.
__device__ __forceinline__ void barrier_nd() {
    asm volatile("s_waitcnt lgkmcnt(0)" ::: "memory");
    __builtin_amdgcn_s_barrier();
    asm volatile("" ::: "memory");
}

// ---------------------------------------------------------------------------
// Kernel 0: weights -> bf16 (unchanged).
// ---------------------------------------------------------------------------
__global__ __launch_bounds__(256) void convw_kernel(
    const float* __restrict__ Wq, const float* __restrict__ bq,
    const float* __restrict__ Wk, const float* __restrict__ bk,
    const float* __restrict__ Wv, const float* __restrict__ bv,
    const float* __restrict__ Wo,
    unsigned short* __restrict__ Wb, unsigned short* __restrict__ Wob,
    float* __restrict__ biasb)
{
    const int row = blockIdx.x;   // 0..255
    const int t = threadIdx.x;    // 0..255
    if (row < 192) {
        const float* W = row < 64 ? Wq : (row < 128 ? Wk : Wv);
        const float sc = row < 64 ? QSCALE : 1.0f;
        f4 v = *(const f4*)&W[(size_t)(row & 63) * ND + t * 4];
        short4v o;
#pragma unroll
        for (int j = 0; j < 4; ++j) o[j] = (short)f2bf(v[j] * sc);
        *(short4v*)&Wb[(size_t)row * ND + t * 4] = o;
        if (row == 0 && t < 192) {
            const float* bsrc = t < 64 ? bq : (t < 128 ? bk : bv);
            biasb[t] = bsrc[t & 63] * (t < 64 ? QSCALE : 1.0f);
        }
    } else if (t < 16) {
        f4 v = *(const f4*)&Wo[(size_t)(row - 192) * 64 + t * 4];
        short4v o;
#pragma unroll
        for (int j = 0; j < 4; ++j) o[j] = (short)f2bf(v[j]);
        *(short4v*)&Wob[(size_t)(row - 192) * 64 + t * 4] = o;
    }
}

// ---------------------------------------------------------------------------
// Kernel 1: QKV projection (R15 exact: 3-deep prefetch, full unroll).
// ---------------------------------------------------------------------------
__global__ __launch_bounds__(512, 2) void qkv_kernel(
    const float* __restrict__ x, const unsigned short* __restrict__ Wb,
    const float* __restrict__ biasb,
    unsigned short* __restrict__ q, unsigned short* __restrict__ k,
    unsigned short* __restrict__ vT)
{
    __shared__ unsigned short As[2][64 * 64];
    __shared__ unsigned short Bs[2][192 * 64];

    const int t = threadIdx.x;
    const int lane = t & 63, g = lane >> 4, li = lane & 15;
    const int w = t >> 6, rg = w >> 2, cg = w & 3;
    const int m0 = blockIdx.x * 64;
    const int arow = t >> 3, ach = t & 7;

    f32x4 acc[2][3];
#pragma unroll
    for (int a = 0; a < 2; ++a)
#pragma unroll
        for (int nf = 0; nf < 3; ++nf) acc[a][nf] = (f32x4)0.f;

    f4 xa[3][2]; short8 wr[3][3];

#define QKV_LOAD(KS, SL)                                                          \
    {                                                                             \
        const float* p_ = &x[(size_t)(m0 + arow) * ND + (KS) * 64 + ach * 8];     \
        xa[SL][0] = *(const f4*)p_; xa[SL][1] = *(const f4*)(p_ + 4);             \
        wr[SL][0] = *(const short8*)&Wb[(size_t)(t >> 3) * ND + (KS) * 64 + (t & 7) * 8];                  \
        wr[SL][1] = *(const short8*)&Wb[(size_t)((t + 512) >> 3) * ND + (KS) * 64 + ((t + 512) & 7) * 8];  \
        wr[SL][2] = *(const short8*)&Wb[(size_t)((t + 1024) >> 3) * ND + (KS) * 64 + ((t + 1024) & 7) * 8];\
    }

#define QKV_COMMIT(SL, BUF)                                                       \
    {                                                                             \
        short8 av_;                                                               \
        for (int j_ = 0; j_ < 4; ++j_) {                                          \
            av_[j_] = (short)f2bf(xa[SL][0][j_]);                                 \
            av_[j_ + 4] = (short)f2bf(xa[SL][1][j_]);                             \
        }                                                                         \
        *(short8*)&As[BUF][arow * 64 + ((ach ^ (arow & 7)) << 3)] = av_;          \
        int r0_ = t >> 3, c0_ = t & 7;                                            \
        *(short8*)&Bs[BUF][r0_ * 64 + ((c0_ ^ (r0_ & 7)) << 3)] = wr[SL][0];      \
        int r1_ = (t + 512) >> 3, c1_ = (t + 512) & 7;                            \
        *(short8*)&Bs[BUF][r1_ * 64 + ((c1_ ^ (r1_ & 7)) << 3)] = wr[SL][1];      \
        int r2_ = (t + 1024) >> 3, c2_ = (t + 1024) & 7;                          \
        *(short8*)&Bs[BUF][r2_ * 64 + ((c2_ ^ (r2_ & 7)) << 3)] = wr[SL][2];      \
    }

    QKV_LOAD(0, 0);
    QKV_LOAD(1, 1);
    QKV_LOAD(2, 2);
    QKV_COMMIT(0, 0);
    barrier_nd();

#pragma unroll
    for (int ks = 0; ks < 16; ++ks) {
        const int cur = ks & 1;
        if (ks < 13) QKV_LOAD(ks + 3, (ks + 3) % 3);
#pragma unroll
        for (int h = 0; h < 2; ++h) {
            short8 af0 = *(const short8*)&As[cur][(rg * 32 + 0 + li) * 64 + (((g + 4 * h) ^ (li & 7)) << 3)];
            short8 af1 = *(const short8*)&As[cur][(rg * 32 + 16 + li) * 64 + (((g + 4 * h) ^ (li & 7)) << 3)];
#pragma unroll
            for (int nf = 0; nf < 3; ++nf) {
                short8 bf = *(const short8*)&Bs[cur][(cg * 48 + nf * 16 + li) * 64 + (((g + 4 * h) ^ (li & 7)) << 3)];
                acc[0][nf] = __builtin_amdgcn_mfma_f32_16x16x32_bf16(af0, bf, acc[0][nf], 0, 0, 0);
                acc[1][nf] = __builtin_amdgcn_mfma_f32_16x16x32_bf16(af1, bf, acc[1][nf], 0, 0, 0);
            }
        }
        if (ks < 15) QKV_COMMIT((ks + 1) % 3, cur ^ 1);
        barrier_nd();
    }

    // epilogue: bias + store (q,k row-major; v transposed [b][h][s])
#pragma unroll
    for (int nf = 0; nf < 3; ++nf) {
        const int col = cg * 48 + nf * 16 + li;
        const float bias = biasb[col];
#pragma unroll
        for (int a = 0; a < 2; ++a) {
            const int row0 = m0 + rg * 32 + a * 16 + 4 * g;
            if (col < 64) {
#pragma unroll
                for (int i = 0; i < 4; ++i)
                    q[(size_t)(row0 + i) * NH + col] = f2bf(acc[a][nf][i] + bias);
            } else if (col < 128) {
#pragma unroll
                for (int i = 0; i < 4; ++i)
                    k[(size_t)(row0 + i) * NH + (col - 64)] = f2bf(acc[a][nf][i] + bias);
            } else {
                short4v pk;
#pragma unroll
                for (int i = 0; i < 4; ++i) pk[i] = (short)f2bf(acc[a][nf][i] + bias);
                const int bb = row0 >> 11, s = row0 & 2047;
                *(short4v*)&vT[(size_t)(bb * NH + (col - 128)) * NS + s] = pk;
            }
        }
    }
}

// ---------------------------------------------------------------------------
// Kernel 2: split-KV causal attention. Block = (batch, 128-row q-block,
// chunk); 4 waves x 32 q-rows each (2 q-halves per wave) so every K/V
// fragment LDS read is amortized over 2x q-rows. Swapped QK^T, packed P.
// ---------------------------------------------------------------------------
__global__ __launch_bounds__(256, 2) void attn_kernel(
    const unsigned short* __restrict__ q, const unsigned short* __restrict__ k,
    const unsigned short* __restrict__ vT,
    float* __restrict__ Opart, float* __restrict__ lpart,
    int ctLog, int MAXC)
{
    __shared__ unsigned short Ks[2][64 * 64];
    __shared__ unsigned short Vs[2][64 * 64];
    __shared__ unsigned short Ps[4][32 * 64];

    const int t = threadIdx.x;
    const int w = t >> 6, lane = t & 63, g = lane >> 4, li = lane & 15;
    const int b = blockIdx.x & 7;          // batch -> XCD pinning
    const int pid = blockIdx.x >> 3;
    const int CT = 1 << ctLog;

    int qb = 0, c = 0;
    {
        int acc = 0;
        for (int u = 15; u >= 0; --u) {    // largest-work-first
            const int nch = (2 * u + 2 + CT - 1) >> ctLog;
            if (pid < acc + nch) { qb = u; c = pid - acc; break; }
            acc += nch;
        }
    }
    const int t0 = c * CT;
    const int ntt = 2 * qb + 2;
    const int rem = ntt - t0;
    const int tcount = rem < CT ? rem : CT;

    const size_t qkbase = (size_t)b * NS * NH;
    const int q0w = qb * 128 + w * 32;     // wave's first q row
    short8 qa[2][2];
#pragma unroll
    for (int qs = 0; qs < 2; ++qs)
#pragma unroll
        for (int h = 0; h < 2; ++h)
            qa[qs][h] = *(const short8*)&q[qkbase + (size_t)(q0w + qs * 16 + li) * NH + h * 32 + g * 8];

    float l_i[2] = {0.f, 0.f};
    f32x4 oacc[2][4];
#pragma unroll
    for (int qs = 0; qs < 2; ++qs)
#pragma unroll
        for (int i = 0; i < 4; ++i) oacc[qs][i] = (f32x4)0.f;

    const int srow = t >> 3, sch = t & 7;
    short8 kreg0, kreg1, vreg0, vreg1;

    {
        const int kv0 = t0 * 64;
        kreg0 = *(const short8*)&k[qkbase + (size_t)(kv0 + srow) * NH + sch * 8];
        kreg1 = *(const short8*)&k[qkbase + (size_t)(kv0 + srow + 32) * NH + sch * 8];
        vreg0 = *(const short8*)&vT[(size_t)(b * NH + srow) * NS + kv0 + sch * 8];
        vreg1 = *(const short8*)&vT[(size_t)(b * NH + srow + 32) * NS + kv0 + sch * 8];
        *(short8*)&Ks[0][srow * 64 + ((sch ^ (srow & 7)) << 3)] = kreg0;
        *(short8*)&Ks[0][(srow + 32) * 64 + ((sch ^ (srow & 7)) << 3)] = kreg1;
        *(short8*)&Vs[0][srow * 64 + ((sch ^ (srow & 7)) << 3)] = vreg0;
        *(short8*)&Vs[0][(srow + 32) * 64 + ((sch ^ (srow & 7)) << 3)] = vreg1;
    }
    barrier_nd();

    for (int tt = 0; tt < tcount; ++tt) {
        const int cur = tt & 1;
        const int kv0 = (t0 + tt) * 64;
        if (tt + 1 < tcount) {   // issue next-tile loads early (T14)
            const int nv0 = kv0 + 64;
            kreg0 = *(const short8*)&k[qkbase + (size_t)(nv0 + srow) * NH + sch * 8];
            kreg1 = *(const short8*)&k[qkbase + (size_t)(nv0 + srow + 32) * NH + sch * 8];
            vreg0 = *(const short8*)&vT[(size_t)(b * NH + srow) * NS + nv0 + sch * 8];
            vreg1 = *(const short8*)&vT[(size_t)(b * NH + srow + 32) * NS + nv0 + sch * 8];
        }
        if (kv0 <= q0w + 31) {             // wave-uniform: tile intersects causal region
            // ---- QK^T swapped: kf shared across both q-halves ----
            f32x4 s[2][4];
#pragma unroll
            for (int c4 = 0; c4 < 4; ++c4) {
                s[0][c4] = (f32x4)0.f; s[1][c4] = (f32x4)0.f;
                const int krow = 16 * c4 + li;
                short8 kf0 = *(const short8*)&Ks[cur][krow * 64 + ((g ^ (li & 7)) << 3)];
                short8 kf1 = *(const short8*)&Ks[cur][krow * 64 + (((g + 4) ^ (li & 7)) << 3)];
                s[0][c4] = __builtin_amdgcn_mfma_f32_16x16x32_bf16(kf0, qa[0][0], s[0][c4], 0, 0, 0);
                s[0][c4] = __builtin_amdgcn_mfma_f32_16x16x32_bf16(kf1, qa[0][1], s[0][c4], 0, 0, 0);
                s[1][c4] = __builtin_amdgcn_mfma_f32_16x16x32_bf16(kf0, qa[1][0], s[1][c4], 0, 0, 0);
                s[1][c4] = __builtin_amdgcn_mfma_f32_16x16x32_bf16(kf1, qa[1][1], s[1][c4], 0, 0, 0);
            }
            // ---- causal mask on diagonal-crossing tiles ----
            if (kv0 + 63 > q0w) {
#pragma unroll
                for (int qs = 0; qs < 2; ++qs)
#pragma unroll
                    for (int c4 = 0; c4 < 4; ++c4)
#pragma unroll
                        for (int i = 0; i < 4; ++i)
                            if (kv0 + 16 * c4 + 4 * g + i > q0w + qs * 16 + li)
                                s[qs][c4][i] = -1e30f;
            }
            // ---- no-max softmax + pack P (per q-half) ----
#pragma unroll
            for (int qs = 0; qs < 2; ++qs) {
                const int prow = qs * 16 + li;
#pragma unroll
                for (int c4 = 0; c4 < 4; ++c4) {
#pragma unroll
                    for (int i = 0; i < 4; ++i) {
                        s[qs][c4][i] = exp2f(fminf(s[qs][c4][i], 80.f));
                        l_i[qs] += s[qs][c4][i];
                    }
                    unsigned lo = (unsigned)f2bf(s[qs][c4][0]) | ((unsigned)f2bf(s[qs][c4][1]) << 16);
                    unsigned hi = (unsigned)f2bf(s[qs][c4][2]) | ((unsigned)f2bf(s[qs][c4][3]) << 16);
                    uint2v pv; pv.x = lo; pv.y = hi;
                    const int chunk = 2 * c4 + (g >> 1);
                    *(uint2v*)&Ps[w][prow * 64 + ((chunk ^ (li & 7)) << 3) + 4 * (g & 1)] = pv;
                }
            }
            // ---- PV: vf shared across both q-halves ----
            short8 pf[2][2];
#pragma unroll
            for (int qs = 0; qs < 2; ++qs) {
                const int prow = qs * 16 + li;
                pf[qs][0] = *(const short8*)&Ps[w][prow * 64 + ((g ^ (li & 7)) << 3)];
                pf[qs][1] = *(const short8*)&Ps[w][prow * 64 + (((g + 4) ^ (li & 7)) << 3)];
            }
#pragma unroll
            for (int nf = 0; nf < 4; ++nf) {
                const int vrow = nf * 16 + li;
                short8 vf0 = *(const short8*)&Vs[cur][vrow * 64 + ((g ^ (li & 7)) << 3)];
                short8 vf1 = *(const short8*)&Vs[cur][vrow * 64 + (((g + 4) ^ (li & 7)) << 3)];
                oacc[0][nf] = __builtin_amdgcn_mfma_f32_16x16x32_bf16(vf0, pf[0][0], oacc[0][nf], 0, 0, 0);
                oacc[0][nf] = __builtin_amdgcn_mfma_f32_16x16x32_bf16(vf1, pf[0][1], oacc[0][nf], 0, 0, 0);
                oacc[1][nf] = __builtin_amdgcn_mfma_f32_16x16x32_bf16(vf0, pf[1][0], oacc[1][nf], 0, 0, 0);
                oacc[1][nf] = __builtin_amdgcn_mfma_f32_16x16x32_bf16(vf1, pf[1][1], oacc[1][nf], 0, 0, 0);
            }
        }
        if (tt + 1 < tcount) {   // commit next tile late
            *(short8*)&Ks[cur ^ 1][srow * 64 + ((sch ^ (srow & 7)) << 3)] = kreg0;
            *(short8*)&Ks[cur ^ 1][(srow + 32) * 64 + ((sch ^ (srow & 7)) << 3)] = kreg1;
            *(short8*)&Vs[cur ^ 1][srow * 64 + ((sch ^ (srow & 7)) << 3)] = vreg0;
            *(short8*)&Vs[cur ^ 1][(srow + 32) * 64 + ((sch ^ (srow & 7)) << 3)] = vreg1;
        }
        barrier_nd();
    }

    // ---- finish l: reduce over the 4 lane-groups holding each q ----
#pragma unroll
    for (int qs = 0; qs < 2; ++qs) {
        l_i[qs] += __shfl_xor(l_i[qs], 16);
        l_i[qs] += __shfl_xor(l_i[qs], 32);
    }

    const size_t slot = (size_t)((b * 16 + qb) * MAXC + c);
    float* Op = Opart + slot * 8192;
#pragma unroll
    for (int qs = 0; qs < 2; ++qs)
#pragma unroll
        for (int nf = 0; nf < 4; ++nf)
#pragma unroll
            for (int i = 0; i < 4; ++i)
                Op[(w * 32 + qs * 16 + li) * 64 + nf * 16 + 4 * g + i] = oacc[qs][nf][i];
    if (g == 0) {
        lpart[slot * 128 + w * 32 + li]      = l_i[0];
        lpart[slot * 128 + w * 32 + 16 + li] = l_i[1];
    }
}

// ---------------------------------------------------------------------------
// Kernel 3: combine partials + MFMA output projection.
// Block = (batch, 128-row q-block, 64-row half). 256 blocks.
// ---------------------------------------------------------------------------
__global__ __launch_bounds__(256, 2) void combine_kernel(
    const float* __restrict__ Opart, const float* __restrict__ lpart,
    const unsigned short* __restrict__ Wob, const float* __restrict__ bo,
    float* __restrict__ out, int ctLog, int MAXC)
{
    __shared__ unsigned short Osm[64 * 64];
    __shared__ float Linv[64];

    const int t = threadIdx.x;
    const int b = blockIdx.x & 7, qb = (blockIdx.x >> 3) & 15, half = blockIdx.x >> 7;
    const int r0 = half * 64;
    const int CT = 1 << ctLog;
    const int nch = (2 * qb + 2 + CT - 1) >> ctLog;
    const size_t base_slot = (size_t)(b * 16 + qb) * MAXC;

    if (t < 64) {
        float L = 0.f;
        for (int cc = 0; cc < nch; ++cc)
            L += lpart[(base_slot + cc) * 128 + r0 + t];
        Linv[t] = 1.f / L;
    }

    // accumulate O' across chunks: thread owns row r (q index), 16 cols
    const int r = t >> 2, c0 = (t & 3) * 16;
    f4 a0 = (f4)0.f, a1 = (f4)0.f, a2 = (f4)0.f, a3 = (f4)0.f;
    for (int cc = 0; cc < nch; ++cc) {
        const float* P = Opart + (base_slot + cc) * 8192 + (r0 + r) * 64 + c0;
        a0 += *(const f4*)P; a1 += *(const f4*)(P + 4);
        a2 += *(const f4*)(P + 8); a3 += *(const f4*)(P + 12);
    }
    __syncthreads();
    {
        const float sc = Linv[r];
        short8 o0, o1;
#pragma unroll
        for (int j = 0; j < 4; ++j) {
            o0[j] = (short)f2bf(a0[j] * sc); o0[j + 4] = (short)f2bf(a1[j] * sc);
            o1[j] = (short)f2bf(a2[j] * sc); o1[j + 4] = (short)f2bf(a3[j] * sc);
        }
        const int ch0 = (t & 3) * 2;
        *(short8*)&Osm[r * 64 + ((ch0 ^ (r & 7)) << 3)] = o0;
        *(short8*)&Osm[r * 64 + (((ch0 + 1) ^ (r & 7)) << 3)] = o1;
    }
    __syncthreads();

    // oproj: 4 waves x 16 rows, MFMA, B = Wo rows (bf16, L2)
    const int w = t >> 6, lane = t & 63, g = lane >> 4, li = lane & 15;
    f32x4 acc[4];
#pragma unroll
    for (int nf = 0; nf < 4; ++nf) acc[nf] = (f32x4)0.f;
#pragma unroll
    for (int s = 0; s < 2; ++s) {
        const int rr = w * 16 + li;
        short8 af = *(const short8*)&Osm[rr * 64 + (((g + 4 * s) ^ (rr & 7)) << 3)];
#pragma unroll
        for (int nf = 0; nf < 4; ++nf) {
            short8 bf = *(const short8*)&Wob[(size_t)(nf * 16 + li) * 64 + s * 32 + g * 8];
            acc[nf] = __builtin_amdgcn_mfma_f32_16x16x32_bf16(af, bf, acc[nf], 0, 0, 0);
        }
    }
#pragma unroll
    for (int nf = 0; nf < 4; ++nf) {
        const float bias = bo[nf * 16 + li];
#pragma unroll
        for (int i = 0; i < 4; ++i) {
            const size_t row = (size_t)b * NS + qb * 128 + r0 + w * 16 + 4 * g + i;
            out[row * 64 + nf * 16 + li] = acc[nf][i] + bias;
        }
    }
}

// ---------------------------------------------------------------------------
extern "C" void kernel_launch(void* const* d_in, const int* in_sizes, int n_in,
                              void* d_out, int out_size, void* d_ws, size_t ws_size,
                              hipStream_t stream)
{
    const float* x  = (const float*)d_in[0];
    const float* Wq = (const float*)d_in[1];
    const float* bq = (const float*)d_in[2];
    const float* Wk = (const float*)d_in[3];
    const float* bk = (const float*)d_in[4];
    const float* Wv = (const float*)d_in[5];
    const float* bv = (const float*)d_in[6];
    const float* Wo = (const float*)d_in[7];
    const float* bo = (const float*)d_in[8];
    float* out = (float*)d_out;

    size_t off = 0;
    auto alloc = [&](size_t bytes) {
        char* p = (char*)d_ws + off;
        off += (bytes + 255) & ~(size_t)255;
        return (void*)p;
    };
    unsigned short* qb  = (unsigned short*)alloc((size_t)NM * NH * 2);
    unsigned short* kb  = (unsigned short*)alloc((size_t)NM * NH * 2);
    unsigned short* vtb = (unsigned short*)alloc((size_t)NM * NH * 2);
    unsigned short* Wb  = (unsigned short*)alloc((size_t)192 * ND * 2);
    unsigned short* Wob = (unsigned short*)alloc((size_t)64 * 64 * 2);
    float* biasb = (float*)alloc(192 * 4);
    const size_t base = off;

    // KV-chunk size (64-row tiles): prefer CT=4 (576 blocks), fall back.
    int ctLog = 5, MAXC = 1;
    const int cands[4] = {2, 3, 4, 5};
    for (int ci = 0; ci < 4; ++ci) {
        const int cl = cands[ci];
        const int mc = 32 >> cl;                 // ceil(32 / CT)
        const size_t nslot = (size_t)128 * mc;   // 8 b x 16 qb x mc
        const size_t need = base + nslot * (8192 + 128) * 4 + 8192;
        if (need <= ws_size) { ctLog = cl; MAXC = mc; break; }
    }
    const size_t NSLOT = (size_t)128 * MAXC;
    float* Opart = (float*)alloc(NSLOT * 8192 * 4);
    float* lpart = (float*)alloc(NSLOT * 128 * 4);

    const int CT = 1 << ctLog;
    int NCperB = 0;
    for (int u = 0; u < 16; ++u) NCperB += (2 * u + 2 + CT - 1) >> ctLog;

    convw_kernel<<<256, 256, 0, stream>>>(Wq, bq, Wk, bk, Wv, bv, Wo, Wb, Wob, biasb);
    qkv_kernel<<<NM / 64, 512, 0, stream>>>(x, Wb, biasb, qb, kb, vtb);
    attn_kernel<<<8 * NCperB, 256, 0, stream>>>(qb, kb, vtb, Opart, lpart, ctLog, MAXC);
    combine_kernel<<<256, 256, 0, stream>>>(Opart, lpart, Wob, bo, out, ctLog, MAXC);
}